// Round 4
// baseline (312.331 us; speedup 1.0000x reference)
//
#include <hip/hip_runtime.h>

typedef unsigned short ushort_t;
typedef __attribute__((ext_vector_type(8))) short short8;
typedef __attribute__((ext_vector_type(4))) float floatx4;

constexpr int F = 256, H = 128, C = 16, HX = 64;
constexpr int NBCOL = H + HX; // 192 fused output cols of GEMM1

__device__ __forceinline__ ushort_t f2bf(float f) {
  unsigned u = __float_as_uint(f);
  u += 0x7fffu + ((u >> 16) & 1u);   // round-to-nearest-even
  return (ushort_t)(u >> 16);
}
__device__ __forceinline__ float bflo(unsigned u) { return __uint_as_float(u << 16); }
__device__ __forceinline__ float bfhi(unsigned u) { return __uint_as_float(u & 0xffff0000u); }

// ---- convert x (f32) -> xb (bf16), 8 elems/thread ----
__global__ void k_conv_x(const float* __restrict__ x, ushort_t* __restrict__ xb, int total8) {
  int i = blockIdx.x * blockDim.x + threadIdx.x;
  if (i >= total8) return;
  const float4* xp = (const float4*)x;
  float4 a = xp[2 * i], b = xp[2 * i + 1];
  ushort4 lo = make_ushort4(f2bf(a.x), f2bf(a.y), f2bf(a.z), f2bf(a.w));
  ushort4 hi = make_ushort4(f2bf(b.x), f2bf(b.y), f2bf(b.z), f2bf(b.w));
  ((ushort4*)xb)[2 * i] = lo;
  ((ushort4*)xb)[2 * i + 1] = hi;
}

// ---- build WBt[n][k] bf16, n in [0,192): cols of [W1 | Wx], transposed ----
__global__ void k_conv_w(const float* __restrict__ W1, const float* __restrict__ Wx,
                         ushort_t* __restrict__ WBt) {
  int i = blockIdx.x * 256 + threadIdx.x;
  if (i >= NBCOL * F) return;
  int nn = i / F, k = i % F;
  float v = (nn < H) ? W1[k * H + nn] : Wx[k * HX + (nn - H)];
  WBt[nn * F + k] = f2bf(v);
}

// ---- in-degree count ----
__global__ void k_count(const int* __restrict__ dst, int* __restrict__ deg, int e) {
  int i = blockIdx.x * 256 + threadIdx.x;
  if (i < e) atomicAdd(&deg[dst[i]], 1);
}

// ---- scan step a: per-block sums ----
__global__ void k_scan_a(const int* __restrict__ deg, int* __restrict__ part, int n) {
  __shared__ int sm[256];
  int i = blockIdx.x * 256 + threadIdx.x;
  int v = (i < n) ? deg[i] : 0;
  sm[threadIdx.x] = v;
  __syncthreads();
  for (int s = 128; s > 0; s >>= 1) {
    if (threadIdx.x < s) sm[threadIdx.x] += sm[threadIdx.x + s];
    __syncthreads();
  }
  if (threadIdx.x == 0) part[blockIdx.x] = sm[0];
}

// ---- scan step b: exclusive scan of <=256 partials ----
__global__ void k_scan_b(const int* __restrict__ part, int* __restrict__ blockoff, int nparts) {
  __shared__ int sm[256];
  int t = threadIdx.x;
  int v = (t < nparts) ? part[t] : 0;
  sm[t] = v;
  __syncthreads();
  for (int d = 1; d < 256; d <<= 1) {
    int add = (t >= d) ? sm[t - d] : 0;
    __syncthreads();
    sm[t] += add;
    __syncthreads();
  }
  blockoff[t] = sm[t] - v;
}

// ---- scan step c: row_start, cursor, dinv ----
__global__ void k_scan_c(const int* __restrict__ deg, const int* __restrict__ blockoff,
                         int* __restrict__ row_start, int* __restrict__ cursor,
                         float* __restrict__ dinv, int n, int e) {
  int i = blockIdx.x * 256 + threadIdx.x;
  int lane = threadIdx.x & 63, wid = threadIdx.x >> 6;
  int v = (i < n) ? deg[i] : 0;
  int x = v;
  for (int d = 1; d < 64; d <<= 1) {
    int t = __shfl_up(x, d);
    if (lane >= d) x += t;
  }
  __shared__ int wsum[4], woff[4];
  if (lane == 63) wsum[wid] = x;
  __syncthreads();
  if (threadIdx.x == 0) {
    int s = 0;
    for (int w = 0; w < 4; w++) { woff[w] = s; s += wsum[w]; }
  }
  __syncthreads();
  int excl = x - v + woff[wid] + blockoff[blockIdx.x];
  if (i < n) {
    row_start[i] = excl;
    cursor[i] = excl;
    dinv[i] = rsqrtf((float)(v + 1));  // +1 self-loop
  }
  if (i == 0) row_start[n] = e;
}

// ---- CSR fill: pack (src, dinv[src]) per edge slot ----
__global__ void k_fill(const int* __restrict__ src, const int* __restrict__ dst,
                       const float* __restrict__ dinv, int* __restrict__ cursor,
                       int2* __restrict__ csr8, int e) {
  int i = blockIdx.x * 256 + threadIdx.x;
  if (i < e) {
    int s = src[i];
    int p = atomicAdd(&cursor[dst[i]], 1);
    csr8[p] = make_int2(s, __float_as_int(dinv[s]));
  }
}

// ---- MFMA GEMM, 4-way col split: xb[64 rows,256] @ WBt[48 cols]^T per block ----
// All 32 VMEM loads (8 A + 24 B) fully unrolled & hoisted: pure ILP, no
// inner-loop loads. ~150 VGPRs live; launch_bounds(256,2) caps at 256.
__global__ __launch_bounds__(256, 2) void k_gemm1(const ushort_t* __restrict__ xb,
                                                  const ushort_t* __restrict__ WBt,
                                                  const float* __restrict__ bx,
                                                  ushort_t* __restrict__ xw1,
                                                  float* __restrict__ xe, int n) {
  int rb = blockIdx.x >> 2, cb = blockIdx.x & 3;
  int w = threadIdx.x >> 6, lane = threadIdx.x & 63;
  int q = lane >> 4, l15 = lane & 15;
  int row = rb * 64 + w * 16 + l15;  // A-operand row: m = lane&15
  int rowc = min(row, n - 1);        // clamp (stores are guarded)
  const short8* arow = (const short8*)(xb + (size_t)rowc * F);
  // B short8 units: (ncol, kk, q) at ncol*32 + kk*4 + q
  const short8* bb0 = (const short8*)(WBt + (size_t)(cb * 48 + 0 * 16 + l15) * F);
  const short8* bb1 = (const short8*)(WBt + (size_t)(cb * 48 + 1 * 16 + l15) * F);
  const short8* bb2 = (const short8*)(WBt + (size_t)(cb * 48 + 2 * 16 + l15) * F);

  short8 a[8], b0[8], b1[8], b2[8];
#pragma unroll
  for (int kk = 0; kk < 8; kk++) {
    a[kk]  = arow[kk * 4 + q];
    b0[kk] = bb0[kk * 4 + q];
    b1[kk] = bb1[kk * 4 + q];
    b2[kk] = bb2[kk * 4 + q];
  }

  floatx4 acc0 = (floatx4)(0.0f), acc1 = (floatx4)(0.0f), acc2 = (floatx4)(0.0f);
#pragma unroll
  for (int kk = 0; kk < 8; kk++) {
    acc0 = __builtin_amdgcn_mfma_f32_16x16x32_bf16(a[kk], b0[kk], acc0, 0, 0, 0);
    acc1 = __builtin_amdgcn_mfma_f32_16x16x32_bf16(a[kk], b1[kk], acc1, 0, 0, 0);
    acc2 = __builtin_amdgcn_mfma_f32_16x16x32_bf16(a[kk], b2[kk], acc2, 0, 0, 0);
  }

  // C/D layout: col = lane&15, row = (lane>>4)*4 + r
  int rbase = rb * 64 + w * 16 + q * 4;
  floatx4 accs[3] = {acc0, acc1, acc2};
#pragma unroll
  for (int t = 0; t < 3; t++) {
    int g = cb * 48 + t * 16;  // global output col base (wave-uniform)
#pragma unroll
    for (int r = 0; r < 4; r++) {
      int ro = rbase + r;
      if (ro < n) {
        if (g < H) {
          xw1[(size_t)ro * H + g + l15] = f2bf(accs[t][r]);
        } else {
          int c2 = g - H + l15;
          float v2 = accs[t][r] + bx[c2];
          xe[(size_t)ro * HX + c2] = fmaxf(v2, 0.0f);
        }
      }
    }
  }
}

// ---- GCN layer 1 aggregation (gather via CSR), one wave per node, x4 unrolled ----
__global__ void k_agg1(const ushort_t* __restrict__ xw1, const int* __restrict__ row_start,
                       const int2* __restrict__ csr8, const float* __restrict__ dinv,
                       const float* __restrict__ b1, float* __restrict__ h, int n) {
  int v = blockIdx.x * 4 + (threadIdx.x >> 6);
  if (v >= n) return;
  int lane = threadIdx.x & 63;
  float dv = dinv[v];
  unsigned sv = ((const unsigned*)(xw1 + (size_t)v * H))[lane];
  float ax = dv * bflo(sv), ay = dv * bfhi(sv);  // self-loop term
  int j0 = row_start[v], j1 = row_start[v + 1];
  int j = j0;
  for (; j + 4 <= j1; j += 4) {
    int2 e0 = csr8[j], e1 = csr8[j + 1], e2 = csr8[j + 2], e3 = csr8[j + 3];
    unsigned r0 = ((const unsigned*)(xw1 + (size_t)e0.x * H))[lane];
    unsigned r1 = ((const unsigned*)(xw1 + (size_t)e1.x * H))[lane];
    unsigned r2 = ((const unsigned*)(xw1 + (size_t)e2.x * H))[lane];
    unsigned r3 = ((const unsigned*)(xw1 + (size_t)e3.x * H))[lane];
    float w0 = __int_as_float(e0.y), w1 = __int_as_float(e1.y);
    float w2 = __int_as_float(e2.y), w3 = __int_as_float(e3.y);
    ax += w0 * bflo(r0) + w1 * bflo(r1) + w2 * bflo(r2) + w3 * bflo(r3);
    ay += w0 * bfhi(r0) + w1 * bfhi(r1) + w2 * bfhi(r2) + w3 * bfhi(r3);
  }
  for (; j < j1; j++) {
    int2 e0 = csr8[j];
    unsigned r0 = ((const unsigned*)(xw1 + (size_t)e0.x * H))[lane];
    float w0 = __int_as_float(e0.y);
    ax += w0 * bflo(r0);
    ay += w0 * bfhi(r0);
  }
  int c = lane * 2;
  float o0 = fmaxf(dv * ax + b1[c], 0.0f);
  float o1 = fmaxf(dv * ay + b1[c + 1], 0.0f);
  ((float2*)(h + (size_t)v * H))[lane] = make_float2(o0, o1);
}

// ---- small GEMM: hw2[n,16] = h[n,128] @ W2[128,16] (no bias) ----
__global__ void k_gemm2(const float* __restrict__ h, const float* __restrict__ W2,
                        float* __restrict__ hw2, int n) {
  int idx = blockIdx.x * 256 + threadIdx.x;
  int node = idx >> 2, cg = idx & 3;
  if (node >= n) return;
  float a0 = 0, a1 = 0, a2 = 0, a3 = 0;
  const float* hr = h + (size_t)node * H;
#pragma unroll 8
  for (int k = 0; k < H; k++) {
    float hv = hr[k];
    float4 w = *(const float4*)(W2 + k * C + cg * 4);
    a0 += hv * w.x; a1 += hv * w.y; a2 += hv * w.z; a3 += hv * w.w;
  }
  *(float4*)(hw2 + (size_t)node * C + cg * 4) = make_float4(a0, a1, a2, a3);
}

// ---- GCN layer 2 aggregation + log_softmax + y_prob; 16 threads per node; x4 unrolled ----
__global__ void k_agg2(const float* __restrict__ hw2, const int* __restrict__ row_start,
                       const int2* __restrict__ csr8, const float* __restrict__ dinv,
                       const float* __restrict__ b2, const int* __restrict__ y,
                       const int* __restrict__ tmask, float* __restrict__ ylp_out,
                       float* __restrict__ yprob, int n) {
  int idx = blockIdx.x * 256 + threadIdx.x;
  int node = idx >> 4, c = idx & 15;
  if (node >= n) return;
  float dv = dinv[node];
  float acc = dv * hw2[(size_t)node * C + c];
  int j0 = row_start[node], j1 = row_start[node + 1];
  int j = j0;
  for (; j + 4 <= j1; j += 4) {
    int2 e0 = csr8[j], e1 = csr8[j + 1], e2 = csr8[j + 2], e3 = csr8[j + 3];
    float r0 = hw2[(size_t)e0.x * C + c];
    float r1 = hw2[(size_t)e1.x * C + c];
    float r2 = hw2[(size_t)e2.x * C + c];
    float r3 = hw2[(size_t)e3.x * C + c];
    acc += __int_as_float(e0.y) * r0 + __int_as_float(e1.y) * r1 +
           __int_as_float(e2.y) * r2 + __int_as_float(e3.y) * r3;
  }
  for (; j < j1; j++) {
    int2 e0 = csr8[j];
    acc += __int_as_float(e0.y) * hw2[(size_t)e0.x * C + c];
  }
  float logit = dv * acc + b2[c];  // TEMP == 1.0
  float m = logit;
  for (int o = 8; o > 0; o >>= 1) m = fmaxf(m, __shfl_xor(m, o, 16));
  float e = expf(logit - m);
  float s16 = e;
  for (int o = 8; o > 0; o >>= 1) s16 += __shfl_xor(s16, o, 16);
  float lp = (logit - m) - logf(s16);
  ylp_out[(size_t)node * C + c] = lp;
  float yp = tmask[node] ? ((y[node] == c) ? 1.0f : 0.0f) : (e / s16);
  yprob[(size_t)node * C + c] = yp;
}

// ---- per-node decode partials: A[v], B[v]; one wave per node ----
__global__ void k_ab(const float* __restrict__ xe, const float* __restrict__ yprob,
                     const float* __restrict__ Wd, float* __restrict__ Aarr,
                     float* __restrict__ Barr, int n) {
  int v = blockIdx.x * 4 + (threadIdx.x >> 6);
  if (v >= n) return;
  int lane = threadIdx.x & 63;
  float xv = xe[(size_t)v * HX + lane];
  float a = xv * Wd[lane];
  float b = xv * Wd[HX + lane];
  if (lane < C) {
    float yv = yprob[(size_t)v * C + lane];
    a += yv * Wd[2 * HX + lane];
    b += yv * Wd[2 * HX + C + lane];
  }
  for (int o = 32; o > 0; o >>= 1) {
    a += __shfl_xor(a, o);
    b += __shfl_xor(b, o);
  }
  if (lane == 0) { Aarr[v] = a; Barr[v] = b; }
}

// ---- edge decode: out = A[s] + B[d] + bd ----
__global__ void k_decode(const int* __restrict__ ei, const int* __restrict__ nei,
                         const float* __restrict__ Aarr, const float* __restrict__ Barr,
                         const float* __restrict__ bd, float* __restrict__ out, int e) {
  int i = blockIdx.x * 256 + threadIdx.x;
  if (i >= 2 * e) return;
  float b0 = bd[0];
  if (i < e) {
    int s = ei[i], d = ei[e + i];
    out[i] = Aarr[s] + Barr[d] + b0;
  } else {
    int j = i - e;
    int s = nei[j], d = nei[e + j];
    out[e + j] = Aarr[s] + Barr[d] + b0;
  }
}

extern "C" void kernel_launch(void* const* d_in, const int* in_sizes, int n_in,
                              void* d_out, int out_size, void* d_ws, size_t ws_size,
                              hipStream_t stream) {
  const float* x = (const float*)d_in[0];
  const int* ei = (const int*)d_in[1];
  const int* nei = (const int*)d_in[2];
  const int* y = (const int*)d_in[3];
  const int* tmask = (const int*)d_in[4];
  const float* W1 = (const float*)d_in[5];
  const float* b1 = (const float*)d_in[6];
  const float* W2 = (const float*)d_in[7];
  const float* b2 = (const float*)d_in[8];
  const float* Wx = (const float*)d_in[9];
  const float* bx = (const float*)d_in[10];
  const float* Wd = (const float*)d_in[11];
  const float* bd = (const float*)d_in[12];
  float* out = (float*)d_out;

  int n = in_sizes[3];        // N nodes
  int e = in_sizes[1] / 2;    // E edges

  char* ws = (char*)d_ws;
  size_t off = 0;
  auto alloc = [&](size_t bytes) -> void* {
    void* p = ws + off;
    off += (bytes + 511) & ~(size_t)511;
    return p;
  };
  ushort_t* xb = (ushort_t*)alloc((size_t)n * F * 2);
  ushort_t* WBt = (ushort_t*)alloc((size_t)NBCOL * F * 2);
  ushort_t* xw1 = (ushort_t*)alloc((size_t)n * H * 2);   // bf16
  float* xe = (float*)alloc((size_t)n * HX * 4);
  float* h = (float*)alloc((size_t)n * H * 4);
  float* hw2 = (float*)alloc((size_t)n * C * 4);
  float* yprob = (float*)alloc((size_t)n * C * 4);
  float* dinv = (float*)alloc((size_t)n * 4);
  int* deg = (int*)alloc((size_t)n * 4);
  int* row_start = (int*)alloc((size_t)(n + 1) * 4);
  int* cursor = (int*)alloc((size_t)n * 4);
  int2* csr8 = (int2*)alloc((size_t)e * 8);
  int* part = (int*)alloc(1024 * 4);
  int* blockoff = (int*)alloc(1024 * 4);
  float* Aarr = (float*)alloc((size_t)n * 4);
  float* Barr = (float*)alloc((size_t)n * 4);

  const int* src = ei;
  const int* dst = ei + e;

  hipMemsetAsync(deg, 0, (size_t)n * 4, stream);

  int total8 = n * F / 8;
  k_conv_x<<<(total8 + 255) / 256, 256, 0, stream>>>(x, xb, total8);
  k_conv_w<<<(NBCOL * F + 255) / 256, 256, 0, stream>>>(W1, Wx, WBt);
  k_count<<<(e + 255) / 256, 256, 0, stream>>>(dst, deg, e);

  int nblk = (n + 255) / 256;  // 196 <= 256, required by k_scan_b
  k_scan_a<<<nblk, 256, 0, stream>>>(deg, part, n);
  k_scan_b<<<1, 256, 0, stream>>>(part, blockoff, nblk);
  k_scan_c<<<nblk, 256, 0, stream>>>(deg, blockoff, row_start, cursor, dinv, n, e);
  k_fill<<<(e + 255) / 256, 256, 0, stream>>>(src, dst, dinv, cursor, csr8, e);

  int nrb = (n + 63) / 64;
  k_gemm1<<<nrb * 4, 256, 0, stream>>>(xb, WBt, bx, xw1, xe, n);
  k_agg1<<<(n + 3) / 4, 256, 0, stream>>>(xw1, row_start, csr8, dinv, b1, h, n);
  k_gemm2<<<(n * 4 + 255) / 256, 256, 0, stream>>>(h, W2, hw2, n);
  k_agg2<<<(n * 16 + 255) / 256, 256, 0, stream>>>(hw2, row_start, csr8, dinv, b2, y,
                                                   tmask, out + (size_t)2 * e, yprob, n);
  k_ab<<<(n + 3) / 4, 256, 0, stream>>>(xe, yprob, Wd, Aarr, Barr, n);
  k_decode<<<(2 * e + 255) / 256, 256, 0, stream>>>(ei, nei, Aarr, Barr, bd, out, e);
}

// Round 5
// 298.395 us; speedup vs baseline: 1.0467x; 1.0467x over previous
//
#include <hip/hip_runtime.h>

typedef unsigned short ushort_t;
typedef __attribute__((ext_vector_type(8))) short short8;
typedef __attribute__((ext_vector_type(4))) float floatx4;

constexpr int F = 256, H = 128, C = 16, HX = 64;
constexpr int NBCOL = H + HX; // 192 fused output cols of GEMM1

__device__ __forceinline__ ushort_t f2bf(float f) {
  unsigned u = __float_as_uint(f);
  u += 0x7fffu + ((u >> 16) & 1u);   // round-to-nearest-even
  return (ushort_t)(u >> 16);
}
__device__ __forceinline__ float bflo(unsigned u) { return __uint_as_float(u << 16); }
__device__ __forceinline__ float bfhi(unsigned u) { return __uint_as_float(u & 0xffff0000u); }

// async global->LDS, 16B per lane; LDS dest = wave-uniform base + lane*16
__device__ __forceinline__ void gld16(const void* g, void* l) {
  __builtin_amdgcn_global_load_lds(
      (const __attribute__((address_space(1))) void*)g,
      (__attribute__((address_space(3))) void*)l, 16, 0, 0);
}

// ---- convert x (f32) -> xb (bf16), 8 elems/thread ----
__global__ void k_conv_x(const float* __restrict__ x, ushort_t* __restrict__ xb, int total8) {
  int i = blockIdx.x * blockDim.x + threadIdx.x;
  if (i >= total8) return;
  const float4* xp = (const float4*)x;
  float4 a = xp[2 * i], b = xp[2 * i + 1];
  ushort4 lo = make_ushort4(f2bf(a.x), f2bf(a.y), f2bf(a.z), f2bf(a.w));
  ushort4 hi = make_ushort4(f2bf(b.x), f2bf(b.y), f2bf(b.z), f2bf(b.w));
  ((ushort4*)xb)[2 * i] = lo;
  ((ushort4*)xb)[2 * i + 1] = hi;
}

// ---- build WBt[n][k] bf16, n in [0,192): cols of [W1 | Wx], transposed ----
__global__ void k_conv_w(const float* __restrict__ W1, const float* __restrict__ Wx,
                         ushort_t* __restrict__ WBt) {
  int i = blockIdx.x * 256 + threadIdx.x;
  if (i >= NBCOL * F) return;
  int nn = i / F, k = i % F;
  float v = (nn < H) ? W1[k * H + nn] : Wx[k * HX + (nn - H)];
  WBt[nn * F + k] = f2bf(v);
}

// ---- in-degree count ----
__global__ void k_count(const int* __restrict__ dst, int* __restrict__ deg, int e) {
  int i = blockIdx.x * 256 + threadIdx.x;
  if (i < e) atomicAdd(&deg[dst[i]], 1);
}

// ---- scan step a: per-block sums ----
__global__ void k_scan_a(const int* __restrict__ deg, int* __restrict__ part, int n) {
  __shared__ int sm[256];
  int i = blockIdx.x * 256 + threadIdx.x;
  int v = (i < n) ? deg[i] : 0;
  sm[threadIdx.x] = v;
  __syncthreads();
  for (int s = 128; s > 0; s >>= 1) {
    if (threadIdx.x < s) sm[threadIdx.x] += sm[threadIdx.x + s];
    __syncthreads();
  }
  if (threadIdx.x == 0) part[blockIdx.x] = sm[0];
}

// ---- scan step b: exclusive scan of <=256 partials ----
__global__ void k_scan_b(const int* __restrict__ part, int* __restrict__ blockoff, int nparts) {
  __shared__ int sm[256];
  int t = threadIdx.x;
  int v = (t < nparts) ? part[t] : 0;
  sm[t] = v;
  __syncthreads();
  for (int d = 1; d < 256; d <<= 1) {
    int add = (t >= d) ? sm[t - d] : 0;
    __syncthreads();
    sm[t] += add;
    __syncthreads();
  }
  blockoff[t] = sm[t] - v;
}

// ---- scan step c: row_start, cursor, dinv ----
__global__ void k_scan_c(const int* __restrict__ deg, const int* __restrict__ blockoff,
                         int* __restrict__ row_start, int* __restrict__ cursor,
                         float* __restrict__ dinv, int n, int e) {
  int i = blockIdx.x * 256 + threadIdx.x;
  int lane = threadIdx.x & 63, wid = threadIdx.x >> 6;
  int v = (i < n) ? deg[i] : 0;
  int x = v;
  for (int d = 1; d < 64; d <<= 1) {
    int t = __shfl_up(x, d);
    if (lane >= d) x += t;
  }
  __shared__ int wsum[4], woff[4];
  if (lane == 63) wsum[wid] = x;
  __syncthreads();
  if (threadIdx.x == 0) {
    int s = 0;
    for (int w = 0; w < 4; w++) { woff[w] = s; s += wsum[w]; }
  }
  __syncthreads();
  int excl = x - v + woff[wid] + blockoff[blockIdx.x];
  if (i < n) {
    row_start[i] = excl;
    cursor[i] = excl;
    dinv[i] = rsqrtf((float)(v + 1));  // +1 self-loop
  }
  if (i == 0) row_start[n] = e;
}

// ---- CSR fill: pack (src, dinv[src]) per edge slot ----
__global__ void k_fill(const int* __restrict__ src, const int* __restrict__ dst,
                       const float* __restrict__ dinv, int* __restrict__ cursor,
                       int2* __restrict__ csr8, int e) {
  int i = blockIdx.x * 256 + threadIdx.x;
  if (i < e) {
    int s = src[i];
    int p = atomicAdd(&cursor[dst[i]], 1);
    csr8[p] = make_int2(s, __float_as_int(dinv[s]));
  }
}

// ---- MFMA GEMM via LDS staging (global_load_lds width=16) ----
// Block = 32 rows x 96 cols. LDS: B-slice 48KB + A-tile 16KB = 64KB (2 blocks/CU).
// 64 async wave-calls stage everything with zero VGPR round-trip; compute is
// ds_read_b128-fed MFMA. Wave w: rows (w&1)*16.., cols (w>>1)*48..
__global__ __launch_bounds__(256, 2) void k_gemm1(const ushort_t* __restrict__ xb,
                                                  const ushort_t* __restrict__ WBt,
                                                  const float* __restrict__ bx,
                                                  ushort_t* __restrict__ xw1,
                                                  float* __restrict__ xe, int n) {
  __shared__ char smem[65536];            // [0,48K): B chunks, [48K,64K): A chunks
  char* b_lds = smem;
  char* a_lds = smem + 48 * 1024;
  int rb = blockIdx.x >> 1, cb = blockIdx.x & 1;
  int w = threadIdx.x >> 6, lane = threadIdx.x & 63;
  int q = lane >> 4, l15 = lane & 15;

  // ---- stage B: 48 chunks of 1KB (chunk c = t*8+kk); wave w -> c in [w*12, w*12+12)
  // chunk layout: lane (q,l15) -> col cb*96+t*16+l15, k-bytes (kk*4+q)*16
#pragma unroll
  for (int i = 0; i < 12; i++) {
    int c = w * 12 + i;
    int t = c >> 3, kk = c & 7;
    const ushort_t* g = WBt + (size_t)(cb * 96 + t * 16 + l15) * F + (kk * 4 + q) * 8;
    gld16(g, b_lds + c * 1024);
  }
  // ---- stage A: 16 calls of 1KB (call j covers chunks 2j,2j+1; chunk = kq, 32 rows x 16B)
#pragma unroll
  for (int i = 0; i < 4; i++) {
    int j = w * 4 + i;
    int c = 2 * j + (lane >> 5);          // k-chunk 0..31
    int rowc = min(rb * 32 + (lane & 31), n - 1);
    const ushort_t* g = xb + (size_t)rowc * F + c * 8;
    gld16(g, a_lds + j * 1024);
  }
  __syncthreads();  // compiler emits s_waitcnt vmcnt(0) before s_barrier

  int rw = w & 1, cw = w >> 1;
  floatx4 acc0 = (floatx4)(0.0f), acc1 = (floatx4)(0.0f), acc2 = (floatx4)(0.0f);
#pragma unroll
  for (int kk = 0; kk < 8; kk++) {
    short8 af = *(const short8*)(a_lds + (kk * 4 + q) * 512 + (rw * 16 + l15) * 16);
    short8 b0 = *(const short8*)(b_lds + ((cw * 3 + 0) * 8 + kk) * 1024 + lane * 16);
    short8 b1 = *(const short8*)(b_lds + ((cw * 3 + 1) * 8 + kk) * 1024 + lane * 16);
    short8 b2 = *(const short8*)(b_lds + ((cw * 3 + 2) * 8 + kk) * 1024 + lane * 16);
    acc0 = __builtin_amdgcn_mfma_f32_16x16x32_bf16(af, b0, acc0, 0, 0, 0);
    acc1 = __builtin_amdgcn_mfma_f32_16x16x32_bf16(af, b1, acc1, 0, 0, 0);
    acc2 = __builtin_amdgcn_mfma_f32_16x16x32_bf16(af, b2, acc2, 0, 0, 0);
  }

  // C/D layout: col = lane&15, row = (lane>>4)*4 + r
  int rbase = rb * 32 + rw * 16 + q * 4;
  floatx4 accs[3] = {acc0, acc1, acc2};
#pragma unroll
  for (int t = 0; t < 3; t++) {
    int g = cb * 96 + cw * 48 + t * 16;   // global output col base (wave-uniform)
#pragma unroll
    for (int r = 0; r < 4; r++) {
      int ro = rbase + r;
      if (ro < n) {
        if (g < H) {
          xw1[(size_t)ro * H + g + l15] = f2bf(accs[t][r]);
        } else {
          int c2 = g - H + l15;
          float v2 = accs[t][r] + bx[c2];
          xe[(size_t)ro * HX + c2] = fmaxf(v2, 0.0f);
        }
      }
    }
  }
}

// ---- GCN layer 1 aggregation (gather via CSR), one wave per node, x4 unrolled ----
__global__ void k_agg1(const ushort_t* __restrict__ xw1, const int* __restrict__ row_start,
                       const int2* __restrict__ csr8, const float* __restrict__ dinv,
                       const float* __restrict__ b1, float* __restrict__ h, int n) {
  int v = blockIdx.x * 4 + (threadIdx.x >> 6);
  if (v >= n) return;
  int lane = threadIdx.x & 63;
  float dv = dinv[v];
  unsigned sv = ((const unsigned*)(xw1 + (size_t)v * H))[lane];
  float ax = dv * bflo(sv), ay = dv * bfhi(sv);  // self-loop term
  int j0 = row_start[v], j1 = row_start[v + 1];
  int j = j0;
  for (; j + 4 <= j1; j += 4) {
    int2 e0 = csr8[j], e1 = csr8[j + 1], e2 = csr8[j + 2], e3 = csr8[j + 3];
    unsigned r0 = ((const unsigned*)(xw1 + (size_t)e0.x * H))[lane];
    unsigned r1 = ((const unsigned*)(xw1 + (size_t)e1.x * H))[lane];
    unsigned r2 = ((const unsigned*)(xw1 + (size_t)e2.x * H))[lane];
    unsigned r3 = ((const unsigned*)(xw1 + (size_t)e3.x * H))[lane];
    float w0 = __int_as_float(e0.y), w1 = __int_as_float(e1.y);
    float w2 = __int_as_float(e2.y), w3 = __int_as_float(e3.y);
    ax += w0 * bflo(r0) + w1 * bflo(r1) + w2 * bflo(r2) + w3 * bflo(r3);
    ay += w0 * bfhi(r0) + w1 * bfhi(r1) + w2 * bfhi(r2) + w3 * bfhi(r3);
  }
  for (; j < j1; j++) {
    int2 e0 = csr8[j];
    unsigned r0 = ((const unsigned*)(xw1 + (size_t)e0.x * H))[lane];
    float w0 = __int_as_float(e0.y);
    ax += w0 * bflo(r0);
    ay += w0 * bfhi(r0);
  }
  int c = lane * 2;
  float o0 = fmaxf(dv * ax + b1[c], 0.0f);
  float o1 = fmaxf(dv * ay + b1[c + 1], 0.0f);
  ((float2*)(h + (size_t)v * H))[lane] = make_float2(o0, o1);
}

// ---- small GEMM: hw2[n,16] = h[n,128] @ W2[128,16] (no bias) ----
__global__ void k_gemm2(const float* __restrict__ h, const float* __restrict__ W2,
                        float* __restrict__ hw2, int n) {
  int idx = blockIdx.x * 256 + threadIdx.x;
  int node = idx >> 2, cg = idx & 3;
  if (node >= n) return;
  float a0 = 0, a1 = 0, a2 = 0, a3 = 0;
  const float* hr = h + (size_t)node * H;
#pragma unroll 8
  for (int k = 0; k < H; k++) {
    float hv = hr[k];
    float4 w = *(const float4*)(W2 + k * C + cg * 4);
    a0 += hv * w.x; a1 += hv * w.y; a2 += hv * w.z; a3 += hv * w.w;
  }
  *(float4*)(hw2 + (size_t)node * C + cg * 4) = make_float4(a0, a1, a2, a3);
}

// ---- GCN layer 2 aggregation + log_softmax + y_prob; 16 threads per node; x4 unrolled ----
__global__ void k_agg2(const float* __restrict__ hw2, const int* __restrict__ row_start,
                       const int2* __restrict__ csr8, const float* __restrict__ dinv,
                       const float* __restrict__ b2, const int* __restrict__ y,
                       const int* __restrict__ tmask, float* __restrict__ ylp_out,
                       float* __restrict__ yprob, int n) {
  int idx = blockIdx.x * 256 + threadIdx.x;
  int node = idx >> 4, c = idx & 15;
  if (node >= n) return;
  float dv = dinv[node];
  float acc = dv * hw2[(size_t)node * C + c];
  int j0 = row_start[node], j1 = row_start[node + 1];
  int j = j0;
  for (; j + 4 <= j1; j += 4) {
    int2 e0 = csr8[j], e1 = csr8[j + 1], e2 = csr8[j + 2], e3 = csr8[j + 3];
    float r0 = hw2[(size_t)e0.x * C + c];
    float r1 = hw2[(size_t)e1.x * C + c];
    float r2 = hw2[(size_t)e2.x * C + c];
    float r3 = hw2[(size_t)e3.x * C + c];
    acc += __int_as_float(e0.y) * r0 + __int_as_float(e1.y) * r1 +
           __int_as_float(e2.y) * r2 + __int_as_float(e3.y) * r3;
  }
  for (; j < j1; j++) {
    int2 e0 = csr8[j];
    acc += __int_as_float(e0.y) * hw2[(size_t)e0.x * C + c];
  }
  float logit = dv * acc + b2[c];  // TEMP == 1.0
  float m = logit;
  for (int o = 8; o > 0; o >>= 1) m = fmaxf(m, __shfl_xor(m, o, 16));
  float e = expf(logit - m);
  float s16 = e;
  for (int o = 8; o > 0; o >>= 1) s16 += __shfl_xor(s16, o, 16);
  float lp = (logit - m) - logf(s16);
  ylp_out[(size_t)node * C + c] = lp;
  float yp = tmask[node] ? ((y[node] == c) ? 1.0f : 0.0f) : (e / s16);
  yprob[(size_t)node * C + c] = yp;
}

// ---- per-node decode partials: A[v], B[v]; one wave per node ----
__global__ void k_ab(const float* __restrict__ xe, const float* __restrict__ yprob,
                     const float* __restrict__ Wd, float* __restrict__ Aarr,
                     float* __restrict__ Barr, int n) {
  int v = blockIdx.x * 4 + (threadIdx.x >> 6);
  if (v >= n) return;
  int lane = threadIdx.x & 63;
  float xv = xe[(size_t)v * HX + lane];
  float a = xv * Wd[lane];
  float b = xv * Wd[HX + lane];
  if (lane < C) {
    float yv = yprob[(size_t)v * C + lane];
    a += yv * Wd[2 * HX + lane];
    b += yv * Wd[2 * HX + C + lane];
  }
  for (int o = 32; o > 0; o >>= 1) {
    a += __shfl_xor(a, o);
    b += __shfl_xor(b, o);
  }
  if (lane == 0) { Aarr[v] = a; Barr[v] = b; }
}

// ---- edge decode: out = A[s] + B[d] + bd ----
__global__ void k_decode(const int* __restrict__ ei, const int* __restrict__ nei,
                         const float* __restrict__ Aarr, const float* __restrict__ Barr,
                         const float* __restrict__ bd, float* __restrict__ out, int e) {
  int i = blockIdx.x * 256 + threadIdx.x;
  if (i >= 2 * e) return;
  float b0 = bd[0];
  if (i < e) {
    int s = ei[i], d = ei[e + i];
    out[i] = Aarr[s] + Barr[d] + b0;
  } else {
    int j = i - e;
    int s = nei[j], d = nei[e + j];
    out[e + j] = Aarr[s] + Barr[d] + b0;
  }
}

extern "C" void kernel_launch(void* const* d_in, const int* in_sizes, int n_in,
                              void* d_out, int out_size, void* d_ws, size_t ws_size,
                              hipStream_t stream) {
  const float* x = (const float*)d_in[0];
  const int* ei = (const int*)d_in[1];
  const int* nei = (const int*)d_in[2];
  const int* y = (const int*)d_in[3];
  const int* tmask = (const int*)d_in[4];
  const float* W1 = (const float*)d_in[5];
  const float* b1 = (const float*)d_in[6];
  const float* W2 = (const float*)d_in[7];
  const float* b2 = (const float*)d_in[8];
  const float* Wx = (const float*)d_in[9];
  const float* bx = (const float*)d_in[10];
  const float* Wd = (const float*)d_in[11];
  const float* bd = (const float*)d_in[12];
  float* out = (float*)d_out;

  int n = in_sizes[3];        // N nodes
  int e = in_sizes[1] / 2;    // E edges

  char* ws = (char*)d_ws;
  size_t off = 0;
  auto alloc = [&](size_t bytes) -> void* {
    void* p = ws + off;
    off += (bytes + 511) & ~(size_t)511;
    return p;
  };
  ushort_t* xb = (ushort_t*)alloc((size_t)n * F * 2);
  ushort_t* WBt = (ushort_t*)alloc((size_t)NBCOL * F * 2);
  ushort_t* xw1 = (ushort_t*)alloc((size_t)n * H * 2);   // bf16
  float* xe = (float*)alloc((size_t)n * HX * 4);
  float* h = (float*)alloc((size_t)n * H * 4);
  float* hw2 = (float*)alloc((size_t)n * C * 4);
  float* yprob = (float*)alloc((size_t)n * C * 4);
  float* dinv = (float*)alloc((size_t)n * 4);
  int* deg = (int*)alloc((size_t)n * 4);
  int* row_start = (int*)alloc((size_t)(n + 1) * 4);
  int* cursor = (int*)alloc((size_t)n * 4);
  int2* csr8 = (int2*)alloc((size_t)e * 8);
  int* part = (int*)alloc(1024 * 4);
  int* blockoff = (int*)alloc(1024 * 4);
  float* Aarr = (float*)alloc((size_t)n * 4);
  float* Barr = (float*)alloc((size_t)n * 4);

  const int* src = ei;
  const int* dst = ei + e;

  hipMemsetAsync(deg, 0, (size_t)n * 4, stream);

  int total8 = n * F / 8;
  k_conv_x<<<(total8 + 255) / 256, 256, 0, stream>>>(x, xb, total8);
  k_conv_w<<<(NBCOL * F + 255) / 256, 256, 0, stream>>>(W1, Wx, WBt);
  k_count<<<(e + 255) / 256, 256, 0, stream>>>(dst, deg, e);

  int nblk = (n + 255) / 256;  // 196 <= 256, required by k_scan_b
  k_scan_a<<<nblk, 256, 0, stream>>>(deg, part, n);
  k_scan_b<<<1, 256, 0, stream>>>(part, blockoff, nblk);
  k_scan_c<<<nblk, 256, 0, stream>>>(deg, blockoff, row_start, cursor, dinv, n, e);
  k_fill<<<(e + 255) / 256, 256, 0, stream>>>(src, dst, dinv, cursor, csr8, e);

  int nrb32 = (n + 31) / 32;
  k_gemm1<<<nrb32 * 2, 256, 0, stream>>>(xb, WBt, bx, xw1, xe, n);
  k_agg1<<<(n + 3) / 4, 256, 0, stream>>>(xw1, row_start, csr8, dinv, b1, h, n);
  k_gemm2<<<(n * 4 + 255) / 256, 256, 0, stream>>>(h, W2, hw2, n);
  k_agg2<<<(n * 16 + 255) / 256, 256, 0, stream>>>(hw2, row_start, csr8, dinv, b2, y,
                                                   tmask, out + (size_t)2 * e, yprob, n);
  k_ab<<<(n + 3) / 4, 256, 0, stream>>>(xe, yprob, Wd, Aarr, Barr, n);
  k_decode<<<(2 * e + 255) / 256, 256, 0, stream>>>(ei, nei, Aarr, Barr, bd, out, e);
}

// Round 6
// 287.419 us; speedup vs baseline: 1.0867x; 1.0382x over previous
//
#include <hip/hip_runtime.h>

typedef unsigned short ushort_t;
typedef __attribute__((ext_vector_type(8))) short short8;
typedef __attribute__((ext_vector_type(4))) float floatx4;

constexpr int F = 256, H = 128, C = 16, HX = 64;
constexpr int NBCOL = H + HX; // 192 fused output cols of GEMM1

__device__ __forceinline__ ushort_t f2bf(float f) {
  unsigned u = __float_as_uint(f);
  u += 0x7fffu + ((u >> 16) & 1u);   // round-to-nearest-even
  return (ushort_t)(u >> 16);
}
__device__ __forceinline__ float bflo(unsigned u) { return __uint_as_float(u << 16); }
__device__ __forceinline__ float bfhi(unsigned u) { return __uint_as_float(u & 0xffff0000u); }

// ---- convert x (f32) -> xb (bf16), 8 elems/thread ----
__global__ void k_conv_x(const float* __restrict__ x, ushort_t* __restrict__ xb, int total8) {
  int i = blockIdx.x * blockDim.x + threadIdx.x;
  if (i >= total8) return;
  const float4* xp = (const float4*)x;
  float4 a = xp[2 * i], b = xp[2 * i + 1];
  ushort4 lo = make_ushort4(f2bf(a.x), f2bf(a.y), f2bf(a.z), f2bf(a.w));
  ushort4 hi = make_ushort4(f2bf(b.x), f2bf(b.y), f2bf(b.z), f2bf(b.w));
  ((ushort4*)xb)[2 * i] = lo;
  ((ushort4*)xb)[2 * i + 1] = hi;
}

// ---- build WBt[n][k] bf16, n in [0,192): cols of [W1 | Wx], transposed ----
__global__ void k_conv_w(const float* __restrict__ W1, const float* __restrict__ Wx,
                         ushort_t* __restrict__ WBt) {
  int i = blockIdx.x * 256 + threadIdx.x;
  if (i >= NBCOL * F) return;
  int nn = i / F, k = i % F;
  float v = (nn < H) ? W1[k * H + nn] : Wx[k * HX + (nn - H)];
  WBt[nn * F + k] = f2bf(v);
}

// ---- in-degree count ----
__global__ void k_count(const int* __restrict__ dst, int* __restrict__ deg, int e) {
  int i = blockIdx.x * 256 + threadIdx.x;
  if (i < e) atomicAdd(&deg[dst[i]], 1);
}

// ---- scan step a: per-block sums ----
__global__ void k_scan_a(const int* __restrict__ deg, int* __restrict__ part, int n) {
  __shared__ int sm[256];
  int i = blockIdx.x * 256 + threadIdx.x;
  int v = (i < n) ? deg[i] : 0;
  sm[threadIdx.x] = v;
  __syncthreads();
  for (int s = 128; s > 0; s >>= 1) {
    if (threadIdx.x < s) sm[threadIdx.x] += sm[threadIdx.x + s];
    __syncthreads();
  }
  if (threadIdx.x == 0) part[blockIdx.x] = sm[0];
}

// ---- scan step b: exclusive scan of <=256 partials ----
__global__ void k_scan_b(const int* __restrict__ part, int* __restrict__ blockoff, int nparts) {
  __shared__ int sm[256];
  int t = threadIdx.x;
  int v = (t < nparts) ? part[t] : 0;
  sm[t] = v;
  __syncthreads();
  for (int d = 1; d < 256; d <<= 1) {
    int add = (t >= d) ? sm[t - d] : 0;
    __syncthreads();
    sm[t] += add;
    __syncthreads();
  }
  blockoff[t] = sm[t] - v;
}

// ---- scan step c: row_start, cursor, dinv ----
__global__ void k_scan_c(const int* __restrict__ deg, const int* __restrict__ blockoff,
                         int* __restrict__ row_start, int* __restrict__ cursor,
                         float* __restrict__ dinv, int n, int e) {
  int i = blockIdx.x * 256 + threadIdx.x;
  int lane = threadIdx.x & 63, wid = threadIdx.x >> 6;
  int v = (i < n) ? deg[i] : 0;
  int x = v;
  for (int d = 1; d < 64; d <<= 1) {
    int t = __shfl_up(x, d);
    if (lane >= d) x += t;
  }
  __shared__ int wsum[4], woff[4];
  if (lane == 63) wsum[wid] = x;
  __syncthreads();
  if (threadIdx.x == 0) {
    int s = 0;
    for (int w = 0; w < 4; w++) { woff[w] = s; s += wsum[w]; }
  }
  __syncthreads();
  int excl = x - v + woff[wid] + blockoff[blockIdx.x];
  if (i < n) {
    row_start[i] = excl;
    cursor[i] = excl;
    dinv[i] = rsqrtf((float)(v + 1));  // +1 self-loop
  }
  if (i == 0) row_start[n] = e;
}

// ---- CSR fill: pack (src, dinv[src]) per edge slot ----
__global__ void k_fill(const int* __restrict__ src, const int* __restrict__ dst,
                       const float* __restrict__ dinv, int* __restrict__ cursor,
                       int2* __restrict__ csr8, int e) {
  int i = blockIdx.x * 256 + threadIdx.x;
  if (i < e) {
    int s = src[i];
    int p = atomicAdd(&cursor[dst[i]], 1);
    csr8[p] = make_int2(s, __float_as_int(dinv[s]));
  }
}

// ---- MFMA GEMM, register-resident B ----
// Whole B = 192x256 bf16 = 96 KB = 24 short8/wave when split 48 cols/wave.
// Each wave hoists its B slice into 96 VGPRs ONCE (loop-invariant -> cannot
// be sunk), then grid-strides over 16-row tiles: 8 coalesced A-loads + 24
// MFMAs. No LDS, no barriers. ~150 VGPR live; (256,3) caps at ~170.
__global__ __launch_bounds__(256, 3) void k_gemm1(const ushort_t* __restrict__ xb,
                                                  const ushort_t* __restrict__ WBt,
                                                  const float* __restrict__ bx,
                                                  ushort_t* __restrict__ xw1,
                                                  float* __restrict__ xe,
                                                  int n, int ntiles) {
  int w = threadIdx.x >> 6, lane = threadIdx.x & 63;
  int q = lane >> 4, l15 = lane & 15;
  // B short8 units: (ncol, kk, q) at ncol*32 + kk*4 + q
  const short8* bb = (const short8*)WBt;
  short8 bfr[3][8];
#pragma unroll
  for (int t = 0; t < 3; t++)
#pragma unroll
    for (int kk = 0; kk < 8; kk++)
      bfr[t][kk] = bb[(size_t)(w * 48 + t * 16 + l15) * 32 + kk * 4 + q];

  float bxv[3];
#pragma unroll
  for (int t = 0; t < 3; t++) {
    int g = w * 48 + t * 16;
    bxv[t] = (g >= H) ? bx[g - H + l15] : 0.0f;
  }

  for (int tile = blockIdx.x; tile < ntiles; tile += gridDim.x) {
    int row = tile * 16 + l15;  // A-operand row: m = lane&15
    const short8* arow = (const short8*)(xb + (size_t)min(row, n - 1) * F);
    short8 a[8];
#pragma unroll
    for (int kk = 0; kk < 8; kk++) a[kk] = arow[kk * 4 + q];

    floatx4 acc0 = (floatx4)(0.0f), acc1 = (floatx4)(0.0f), acc2 = (floatx4)(0.0f);
#pragma unroll
    for (int kk = 0; kk < 8; kk++) {
      acc0 = __builtin_amdgcn_mfma_f32_16x16x32_bf16(a[kk], bfr[0][kk], acc0, 0, 0, 0);
      acc1 = __builtin_amdgcn_mfma_f32_16x16x32_bf16(a[kk], bfr[1][kk], acc1, 0, 0, 0);
      acc2 = __builtin_amdgcn_mfma_f32_16x16x32_bf16(a[kk], bfr[2][kk], acc2, 0, 0, 0);
    }

    // C/D layout: col = lane&15, row = (lane>>4)*4 + r
    floatx4 accs[3] = {acc0, acc1, acc2};
    int rbase = tile * 16 + q * 4;
#pragma unroll
    for (int t = 0; t < 3; t++) {
      int g = w * 48 + t * 16;  // wave-uniform output col base
#pragma unroll
      for (int r = 0; r < 4; r++) {
        int ro = rbase + r;
        if (ro < n) {
          if (g < H) {
            xw1[(size_t)ro * H + g + l15] = f2bf(accs[t][r]);
          } else {
            xe[(size_t)ro * HX + (g - H) + l15] = fmaxf(accs[t][r] + bxv[t], 0.0f);
          }
        }
      }
    }
  }
}

// ---- GCN layer 1 aggregation (gather via CSR), one wave per node, x8 unrolled ----
__global__ void k_agg1(const ushort_t* __restrict__ xw1, const int* __restrict__ row_start,
                       const int2* __restrict__ csr8, const float* __restrict__ dinv,
                       const float* __restrict__ b1, float* __restrict__ h, int n) {
  int v = blockIdx.x * 4 + (threadIdx.x >> 6);
  if (v >= n) return;
  int lane = threadIdx.x & 63;
  float dv = dinv[v];
  unsigned sv = ((const unsigned*)(xw1 + (size_t)v * H))[lane];
  float ax = dv * bflo(sv), ay = dv * bfhi(sv);  // self-loop term
  int j0 = row_start[v], j1 = row_start[v + 1];
  int j = j0;
  for (; j + 8 <= j1; j += 8) {
    int2 ee[8];
    unsigned rr[8];
#pragma unroll
    for (int u = 0; u < 8; u++) ee[u] = csr8[j + u];
#pragma unroll
    for (int u = 0; u < 8; u++)
      rr[u] = ((const unsigned*)(xw1 + (size_t)ee[u].x * H))[lane];
#pragma unroll
    for (int u = 0; u < 8; u++) {
      float wu = __int_as_float(ee[u].y);
      ax += wu * bflo(rr[u]);
      ay += wu * bfhi(rr[u]);
    }
  }
  for (; j < j1; j++) {
    int2 e0 = csr8[j];
    unsigned r0 = ((const unsigned*)(xw1 + (size_t)e0.x * H))[lane];
    float w0 = __int_as_float(e0.y);
    ax += w0 * bflo(r0);
    ay += w0 * bfhi(r0);
  }
  int c = lane * 2;
  float o0 = fmaxf(dv * ax + b1[c], 0.0f);
  float o1 = fmaxf(dv * ay + b1[c + 1], 0.0f);
  ((float2*)(h + (size_t)v * H))[lane] = make_float2(o0, o1);
}

// ---- small GEMM: hw2[n,16] = h[n,128] @ W2[128,16] (no bias) ----
__global__ void k_gemm2(const float* __restrict__ h, const float* __restrict__ W2,
                        float* __restrict__ hw2, int n) {
  int idx = blockIdx.x * 256 + threadIdx.x;
  int node = idx >> 2, cg = idx & 3;
  if (node >= n) return;
  float a0 = 0, a1 = 0, a2 = 0, a3 = 0;
  const float* hr = h + (size_t)node * H;
#pragma unroll 8
  for (int k = 0; k < H; k++) {
    float hv = hr[k];
    float4 w = *(const float4*)(W2 + k * C + cg * 4);
    a0 += hv * w.x; a1 += hv * w.y; a2 += hv * w.z; a3 += hv * w.w;
  }
  *(float4*)(hw2 + (size_t)node * C + cg * 4) = make_float4(a0, a1, a2, a3);
}

// ---- GCN layer 2 aggregation + log_softmax + y_prob; 16 threads per node; x4 unrolled ----
__global__ void k_agg2(const float* __restrict__ hw2, const int* __restrict__ row_start,
                       const int2* __restrict__ csr8, const float* __restrict__ dinv,
                       const float* __restrict__ b2, const int* __restrict__ y,
                       const int* __restrict__ tmask, float* __restrict__ ylp_out,
                       float* __restrict__ yprob, int n) {
  int idx = blockIdx.x * 256 + threadIdx.x;
  int node = idx >> 4, c = idx & 15;
  if (node >= n) return;
  float dv = dinv[node];
  float acc = dv * hw2[(size_t)node * C + c];
  int j0 = row_start[node], j1 = row_start[node + 1];
  int j = j0;
  for (; j + 4 <= j1; j += 4) {
    int2 e0 = csr8[j], e1 = csr8[j + 1], e2 = csr8[j + 2], e3 = csr8[j + 3];
    float r0 = hw2[(size_t)e0.x * C + c];
    float r1 = hw2[(size_t)e1.x * C + c];
    float r2 = hw2[(size_t)e2.x * C + c];
    float r3 = hw2[(size_t)e3.x * C + c];
    acc += __int_as_float(e0.y) * r0 + __int_as_float(e1.y) * r1 +
           __int_as_float(e2.y) * r2 + __int_as_float(e3.y) * r3;
  }
  for (; j < j1; j++) {
    int2 e0 = csr8[j];
    acc += __int_as_float(e0.y) * hw2[(size_t)e0.x * C + c];
  }
  float logit = dv * acc + b2[c];  // TEMP == 1.0
  float m = logit;
  for (int o = 8; o > 0; o >>= 1) m = fmaxf(m, __shfl_xor(m, o, 16));
  float e = expf(logit - m);
  float s16 = e;
  for (int o = 8; o > 0; o >>= 1) s16 += __shfl_xor(s16, o, 16);
  float lp = (logit - m) - logf(s16);
  ylp_out[(size_t)node * C + c] = lp;
  float yp = tmask[node] ? ((y[node] == c) ? 1.0f : 0.0f) : (e / s16);
  yprob[(size_t)node * C + c] = yp;
}

// ---- per-node decode partials: A[v], B[v]; one wave per node ----
__global__ void k_ab(const float* __restrict__ xe, const float* __restrict__ yprob,
                     const float* __restrict__ Wd, float* __restrict__ Aarr,
                     float* __restrict__ Barr, int n) {
  int v = blockIdx.x * 4 + (threadIdx.x >> 6);
  if (v >= n) return;
  int lane = threadIdx.x & 63;
  float xv = xe[(size_t)v * HX + lane];
  float a = xv * Wd[lane];
  float b = xv * Wd[HX + lane];
  if (lane < C) {
    float yv = yprob[(size_t)v * C + lane];
    a += yv * Wd[2 * HX + lane];
    b += yv * Wd[2 * HX + C + lane];
  }
  for (int o = 32; o > 0; o >>= 1) {
    a += __shfl_xor(a, o);
    b += __shfl_xor(b, o);
  }
  if (lane == 0) { Aarr[v] = a; Barr[v] = b; }
}

// ---- edge decode: out = A[s] + B[d] + bd ----
__global__ void k_decode(const int* __restrict__ ei, const int* __restrict__ nei,
                         const float* __restrict__ Aarr, const float* __restrict__ Barr,
                         const float* __restrict__ bd, float* __restrict__ out, int e) {
  int i = blockIdx.x * 256 + threadIdx.x;
  if (i >= 2 * e) return;
  float b0 = bd[0];
  if (i < e) {
    int s = ei[i], d = ei[e + i];
    out[i] = Aarr[s] + Barr[d] + b0;
  } else {
    int j = i - e;
    int s = nei[j], d = nei[e + j];
    out[e + j] = Aarr[s] + Barr[d] + b0;
  }
}

extern "C" void kernel_launch(void* const* d_in, const int* in_sizes, int n_in,
                              void* d_out, int out_size, void* d_ws, size_t ws_size,
                              hipStream_t stream) {
  const float* x = (const float*)d_in[0];
  const int* ei = (const int*)d_in[1];
  const int* nei = (const int*)d_in[2];
  const int* y = (const int*)d_in[3];
  const int* tmask = (const int*)d_in[4];
  const float* W1 = (const float*)d_in[5];
  const float* b1 = (const float*)d_in[6];
  const float* W2 = (const float*)d_in[7];
  const float* b2 = (const float*)d_in[8];
  const float* Wx = (const float*)d_in[9];
  const float* bx = (const float*)d_in[10];
  const float* Wd = (const float*)d_in[11];
  const float* bd = (const float*)d_in[12];
  float* out = (float*)d_out;

  int n = in_sizes[3];        // N nodes
  int e = in_sizes[1] / 2;    // E edges

  char* ws = (char*)d_ws;
  size_t off = 0;
  auto alloc = [&](size_t bytes) -> void* {
    void* p = ws + off;
    off += (bytes + 511) & ~(size_t)511;
    return p;
  };
  ushort_t* xb = (ushort_t*)alloc((size_t)n * F * 2);
  ushort_t* WBt = (ushort_t*)alloc((size_t)NBCOL * F * 2);
  ushort_t* xw1 = (ushort_t*)alloc((size_t)n * H * 2);   // bf16
  float* xe = (float*)alloc((size_t)n * HX * 4);
  float* h = (float*)alloc((size_t)n * H * 4);
  float* hw2 = (float*)alloc((size_t)n * C * 4);
  float* yprob = (float*)alloc((size_t)n * C * 4);
  float* dinv = (float*)alloc((size_t)n * 4);
  int* deg = (int*)alloc((size_t)n * 4);
  int* row_start = (int*)alloc((size_t)(n + 1) * 4);
  int* cursor = (int*)alloc((size_t)n * 4);
  int2* csr8 = (int2*)alloc((size_t)e * 8);
  int* part = (int*)alloc(1024 * 4);
  int* blockoff = (int*)alloc(1024 * 4);
  float* Aarr = (float*)alloc((size_t)n * 4);
  float* Barr = (float*)alloc((size_t)n * 4);

  const int* src = ei;
  const int* dst = ei + e;

  hipMemsetAsync(deg, 0, (size_t)n * 4, stream);

  int total8 = n * F / 8;
  k_conv_x<<<(total8 + 255) / 256, 256, 0, stream>>>(x, xb, total8);
  k_conv_w<<<(NBCOL * F + 255) / 256, 256, 0, stream>>>(W1, Wx, WBt);
  k_count<<<(e + 255) / 256, 256, 0, stream>>>(dst, deg, e);

  int nblk = (n + 255) / 256;  // 196 <= 256, required by k_scan_b
  k_scan_a<<<nblk, 256, 0, stream>>>(deg, part, n);
  k_scan_b<<<1, 256, 0, stream>>>(part, blockoff, nblk);
  k_scan_c<<<nblk, 256, 0, stream>>>(deg, blockoff, row_start, cursor, dinv, n, e);
  k_fill<<<(e + 255) / 256, 256, 0, stream>>>(src, dst, dinv, cursor, csr8, e);

  int ntiles = (n + 15) / 16;
  int ggrid = ntiles < 768 ? ntiles : 768;
  k_gemm1<<<ggrid, 256, 0, stream>>>(xb, WBt, bx, xw1, xe, n, ntiles);
  k_agg1<<<(n + 3) / 4, 256, 0, stream>>>(xw1, row_start, csr8, dinv, b1, h, n);
  k_gemm2<<<(n * 4 + 255) / 256, 256, 0, stream>>>(h, W2, hw2, n);
  k_agg2<<<(n * 16 + 255) / 256, 256, 0, stream>>>(hw2, row_start, csr8, dinv, b2, y,
                                                   tmask, out + (size_t)2 * e, yprob, n);
  k_ab<<<(n + 3) / 4, 256, 0, stream>>>(xe, yprob, Wd, Aarr, Barr, n);
  k_decode<<<(2 * e + 255) / 256, 256, 0, stream>>>(ei, nei, Aarr, Barr, bd, out, e);
}

// Round 7
// 269.800 us; speedup vs baseline: 1.1576x; 1.0653x over previous
//
#include <hip/hip_runtime.h>

typedef unsigned short ushort_t;
typedef __attribute__((ext_vector_type(8))) short short8;
typedef __attribute__((ext_vector_type(4))) float floatx4;

constexpr int F = 256, H = 128, C = 16, HX = 64;
constexpr int NBCOL = H + HX; // 192 fused output cols of GEMM1

__device__ __forceinline__ ushort_t f2bf(float f) {
  unsigned u = __float_as_uint(f);
  u += 0x7fffu + ((u >> 16) & 1u);   // round-to-nearest-even
  return (ushort_t)(u >> 16);
}
__device__ __forceinline__ float bflo(unsigned u) { return __uint_as_float(u << 16); }
__device__ __forceinline__ float bfhi(unsigned u) { return __uint_as_float(u & 0xffff0000u); }

// ---- fat pre-kernel: conv_x | conv_w | count (independent, one launch) ----
__global__ void k_pre(const float* __restrict__ x, ushort_t* __restrict__ xb, int total8,
                      const float* __restrict__ W1, const float* __restrict__ Wx,
                      ushort_t* __restrict__ WBt,
                      const int* __restrict__ dst, int* __restrict__ deg, int e,
                      int nbx, int nbw) {
  int b = blockIdx.x;
  if (b < nbx) {
    int i = b * 256 + threadIdx.x;
    if (i >= total8) return;
    const float4* xp = (const float4*)x;
    float4 a = xp[2 * i], bb = xp[2 * i + 1];
    ushort4 lo = make_ushort4(f2bf(a.x), f2bf(a.y), f2bf(a.z), f2bf(a.w));
    ushort4 hi = make_ushort4(f2bf(bb.x), f2bf(bb.y), f2bf(bb.z), f2bf(bb.w));
    ((ushort4*)xb)[2 * i] = lo;
    ((ushort4*)xb)[2 * i + 1] = hi;
  } else if (b < nbx + nbw) {
    int i = (b - nbx) * 256 + threadIdx.x;
    if (i >= NBCOL * F) return;
    int nn = i / F, k = i % F;
    float v = (nn < H) ? W1[k * H + nn] : Wx[k * HX + (nn - H)];
    WBt[nn * F + k] = f2bf(v);
  } else {
    int i = (b - nbx - nbw) * 256 + threadIdx.x;
    if (i < e) atomicAdd(&deg[dst[i]], 1);
  }
}

// ---- scan step a: per-block sums ----
__global__ void k_scan_a(const int* __restrict__ deg, int* __restrict__ part, int n) {
  __shared__ int sm[256];
  int i = blockIdx.x * 256 + threadIdx.x;
  int v = (i < n) ? deg[i] : 0;
  sm[threadIdx.x] = v;
  __syncthreads();
  for (int s = 128; s > 0; s >>= 1) {
    if (threadIdx.x < s) sm[threadIdx.x] += sm[threadIdx.x + s];
    __syncthreads();
  }
  if (threadIdx.x == 0) part[blockIdx.x] = sm[0];
}

// ---- scan step b: exclusive scan of <=256 partials ----
__global__ void k_scan_b(const int* __restrict__ part, int* __restrict__ blockoff, int nparts) {
  __shared__ int sm[256];
  int t = threadIdx.x;
  int v = (t < nparts) ? part[t] : 0;
  sm[t] = v;
  __syncthreads();
  for (int d = 1; d < 256; d <<= 1) {
    int add = (t >= d) ? sm[t - d] : 0;
    __syncthreads();
    sm[t] += add;
    __syncthreads();
  }
  blockoff[t] = sm[t] - v;
}

// ---- scan step c: row_start, cursor, dinv ----
__global__ void k_scan_c(const int* __restrict__ deg, const int* __restrict__ blockoff,
                         int* __restrict__ row_start, int* __restrict__ cursor,
                         float* __restrict__ dinv, int n, int e) {
  int i = blockIdx.x * 256 + threadIdx.x;
  int lane = threadIdx.x & 63, wid = threadIdx.x >> 6;
  int v = (i < n) ? deg[i] : 0;
  int x = v;
  for (int d = 1; d < 64; d <<= 1) {
    int t = __shfl_up(x, d);
    if (lane >= d) x += t;
  }
  __shared__ int wsum[4], woff[4];
  if (lane == 63) wsum[wid] = x;
  __syncthreads();
  if (threadIdx.x == 0) {
    int s = 0;
    for (int w = 0; w < 4; w++) { woff[w] = s; s += wsum[w]; }
  }
  __syncthreads();
  int excl = x - v + woff[wid] + blockoff[blockIdx.x];
  if (i < n) {
    row_start[i] = excl;
    cursor[i] = excl;
    dinv[i] = rsqrtf((float)(v + 1));  // +1 self-loop
  }
  if (i == 0) row_start[n] = e;
}

// ---- CSR fill: pack (src, dinv[src]) per edge slot ----
__global__ void k_fill(const int* __restrict__ src, const int* __restrict__ dst,
                       const float* __restrict__ dinv, int* __restrict__ cursor,
                       int2* __restrict__ csr8, int e) {
  int i = blockIdx.x * 256 + threadIdx.x;
  if (i < e) {
    int s = src[i];
    int p = atomicAdd(&cursor[dst[i]], 1);
    csr8[p] = make_int2(s, __float_as_int(dinv[s]));
  }
}

// ---- MFMA GEMM, register-resident B (whole B = 96 KB = 24 short8/wave @48 cols) ----
__global__ __launch_bounds__(256, 3) void k_gemm1(const ushort_t* __restrict__ xb,
                                                  const ushort_t* __restrict__ WBt,
                                                  const float* __restrict__ bx,
                                                  ushort_t* __restrict__ xw1,
                                                  float* __restrict__ xe,
                                                  int n, int ntiles) {
  int w = threadIdx.x >> 6, lane = threadIdx.x & 63;
  int q = lane >> 4, l15 = lane & 15;
  const short8* bb = (const short8*)WBt;
  short8 bfr[3][8];
#pragma unroll
  for (int t = 0; t < 3; t++)
#pragma unroll
    for (int kk = 0; kk < 8; kk++)
      bfr[t][kk] = bb[(size_t)(w * 48 + t * 16 + l15) * 32 + kk * 4 + q];

  float bxv[3];
#pragma unroll
  for (int t = 0; t < 3; t++) {
    int g = w * 48 + t * 16;
    bxv[t] = (g >= H) ? bx[g - H + l15] : 0.0f;
  }

  for (int tile = blockIdx.x; tile < ntiles; tile += gridDim.x) {
    int row = tile * 16 + l15;  // A-operand row: m = lane&15
    const short8* arow = (const short8*)(xb + (size_t)min(row, n - 1) * F);
    short8 a[8];
#pragma unroll
    for (int kk = 0; kk < 8; kk++) a[kk] = arow[kk * 4 + q];

    floatx4 acc0 = (floatx4)(0.0f), acc1 = (floatx4)(0.0f), acc2 = (floatx4)(0.0f);
#pragma unroll
    for (int kk = 0; kk < 8; kk++) {
      acc0 = __builtin_amdgcn_mfma_f32_16x16x32_bf16(a[kk], bfr[0][kk], acc0, 0, 0, 0);
      acc1 = __builtin_amdgcn_mfma_f32_16x16x32_bf16(a[kk], bfr[1][kk], acc1, 0, 0, 0);
      acc2 = __builtin_amdgcn_mfma_f32_16x16x32_bf16(a[kk], bfr[2][kk], acc2, 0, 0, 0);
    }

    // C/D layout: col = lane&15, row = (lane>>4)*4 + r
    floatx4 accs[3] = {acc0, acc1, acc2};
    int rbase = tile * 16 + q * 4;
#pragma unroll
    for (int t = 0; t < 3; t++) {
      int g = w * 48 + t * 16;  // wave-uniform output col base
#pragma unroll
      for (int r = 0; r < 4; r++) {
        int ro = rbase + r;
        if (ro < n) {
          if (g < H) {
            xw1[(size_t)ro * H + g + l15] = f2bf(accs[t][r]);
          } else {
            xe[(size_t)ro * HX + (g - H) + l15] = fmaxf(accs[t][r] + bxv[t], 0.0f);
          }
        }
      }
    }
  }
}

// ---- GCN layer 1 aggregation (gather via CSR), one wave per node, x8 unrolled ----
// Output h in bf16 (only consumed by gemm2).
__global__ void k_agg1(const ushort_t* __restrict__ xw1, const int* __restrict__ row_start,
                       const int2* __restrict__ csr8, const float* __restrict__ dinv,
                       const float* __restrict__ b1, ushort_t* __restrict__ hb, int n) {
  int v = blockIdx.x * 4 + (threadIdx.x >> 6);
  if (v >= n) return;
  int lane = threadIdx.x & 63;
  float dv = dinv[v];
  unsigned sv = ((const unsigned*)(xw1 + (size_t)v * H))[lane];
  float ax = dv * bflo(sv), ay = dv * bfhi(sv);  // self-loop term
  int j0 = row_start[v], j1 = row_start[v + 1];
  int j = j0;
  for (; j + 8 <= j1; j += 8) {
    int2 ee[8];
    unsigned rr[8];
#pragma unroll
    for (int u = 0; u < 8; u++) ee[u] = csr8[j + u];
#pragma unroll
    for (int u = 0; u < 8; u++)
      rr[u] = ((const unsigned*)(xw1 + (size_t)ee[u].x * H))[lane];
#pragma unroll
    for (int u = 0; u < 8; u++) {
      float wu = __int_as_float(ee[u].y);
      ax += wu * bflo(rr[u]);
      ay += wu * bfhi(rr[u]);
    }
  }
  for (; j < j1; j++) {
    int2 e0 = csr8[j];
    unsigned r0 = ((const unsigned*)(xw1 + (size_t)e0.x * H))[lane];
    float w0 = __int_as_float(e0.y);
    ax += w0 * bflo(r0);
    ay += w0 * bfhi(r0);
  }
  int c = lane * 2;
  float o0 = fmaxf(dv * ax + b1[c], 0.0f);
  float o1 = fmaxf(dv * ay + b1[c + 1], 0.0f);
  unsigned hv = (unsigned)f2bf(o0) | ((unsigned)f2bf(o1) << 16);
  ((unsigned*)(hb + (size_t)v * H))[lane] = hv;
}

// ---- small GEMM: hw2[n,16] = h_bf16[n,128] @ W2[128,16] (no bias) ----
__global__ void k_gemm2(const ushort_t* __restrict__ hb, const float* __restrict__ W2,
                        float* __restrict__ hw2, int n) {
  int idx = blockIdx.x * 256 + threadIdx.x;
  int node = idx >> 2, cg = idx & 3;
  if (node >= n) return;
  float a0 = 0, a1 = 0, a2 = 0, a3 = 0;
  const unsigned* hr = (const unsigned*)(hb + (size_t)node * H);
#pragma unroll 8
  for (int k2 = 0; k2 < 64; k2++) {
    unsigned u = hr[k2];
    float h0 = bflo(u), h1 = bfhi(u);
    float4 w0 = *(const float4*)(W2 + (2 * k2) * C + cg * 4);
    float4 w1 = *(const float4*)(W2 + (2 * k2 + 1) * C + cg * 4);
    a0 += h0 * w0.x + h1 * w1.x;
    a1 += h0 * w0.y + h1 * w1.y;
    a2 += h0 * w0.z + h1 * w1.z;
    a3 += h0 * w0.w + h1 * w1.w;
  }
  *(float4*)(hw2 + (size_t)node * C + cg * 4) = make_float4(a0, a1, a2, a3);
}

// ---- GCN layer 2 agg + log_softmax + fused decode partials A[v],B[v] ----
// 16 threads/node; yprob never materialized.
__global__ void k_agg2ab(const float* __restrict__ hw2, const int* __restrict__ row_start,
                         const int2* __restrict__ csr8, const float* __restrict__ dinv,
                         const float* __restrict__ b2, const int* __restrict__ y,
                         const int* __restrict__ tmask, const float* __restrict__ xe,
                         const float* __restrict__ Wd, float* __restrict__ ylp_out,
                         float* __restrict__ Aarr, float* __restrict__ Barr, int n) {
  int idx = blockIdx.x * 256 + threadIdx.x;
  int node = idx >> 4, c = idx & 15;
  if (node >= n) return;
  float dv = dinv[node];
  float acc = dv * hw2[(size_t)node * C + c];
  int j0 = row_start[node], j1 = row_start[node + 1];
  int j = j0;
  for (; j + 8 <= j1; j += 8) {
    int2 ee[8];
    float rr[8];
#pragma unroll
    for (int u = 0; u < 8; u++) ee[u] = csr8[j + u];
#pragma unroll
    for (int u = 0; u < 8; u++) rr[u] = hw2[(size_t)ee[u].x * C + c];
#pragma unroll
    for (int u = 0; u < 8; u++) acc += __int_as_float(ee[u].y) * rr[u];
  }
  for (; j + 4 <= j1; j += 4) {
    int2 e0 = csr8[j], e1 = csr8[j + 1], e2 = csr8[j + 2], e3 = csr8[j + 3];
    float r0 = hw2[(size_t)e0.x * C + c];
    float r1 = hw2[(size_t)e1.x * C + c];
    float r2 = hw2[(size_t)e2.x * C + c];
    float r3 = hw2[(size_t)e3.x * C + c];
    acc += __int_as_float(e0.y) * r0 + __int_as_float(e1.y) * r1 +
           __int_as_float(e2.y) * r2 + __int_as_float(e3.y) * r3;
  }
  for (; j < j1; j++) {
    int2 e0 = csr8[j];
    acc += __int_as_float(e0.y) * hw2[(size_t)e0.x * C + c];
  }
  float logit = dv * acc + b2[c];  // TEMP == 1.0
  float m = logit;
  for (int o = 8; o > 0; o >>= 1) m = fmaxf(m, __shfl_xor(m, o, 16));
  float e = expf(logit - m);
  float s16 = e;
  for (int o = 8; o > 0; o >>= 1) s16 += __shfl_xor(s16, o, 16);
  float lp = (logit - m) - logf(s16);
  ylp_out[(size_t)node * C + c] = lp;
  float yp = tmask[node] ? ((y[node] == c) ? 1.0f : 0.0f) : (e / s16);

  // decode partials: A[v] = xe[v].Wd[0:64] + yp[v].Wd[128:144]
  //                  B[v] = xe[v].Wd[64:128] + yp[v].Wd[144:160]
  float4 xv = *(const float4*)(xe + (size_t)node * HX + c * 4);
  float4 wa = *(const float4*)(Wd + c * 4);
  float4 wb = *(const float4*)(Wd + HX + c * 4);
  float pa = xv.x * wa.x + xv.y * wa.y + xv.z * wa.z + xv.w * wa.w + yp * Wd[2 * HX + c];
  float pb = xv.x * wb.x + xv.y * wb.y + xv.z * wb.z + xv.w * wb.w + yp * Wd[2 * HX + C + c];
  for (int o = 8; o > 0; o >>= 1) {
    pa += __shfl_xor(pa, o, 16);
    pb += __shfl_xor(pb, o, 16);
  }
  if (c == 0) { Aarr[node] = pa; Barr[node] = pb; }
}

// ---- edge decode: out = A[s] + B[d] + bd ----
__global__ void k_decode(const int* __restrict__ ei, const int* __restrict__ nei,
                         const float* __restrict__ Aarr, const float* __restrict__ Barr,
                         const float* __restrict__ bd, float* __restrict__ out, int e) {
  int i = blockIdx.x * 256 + threadIdx.x;
  if (i >= 2 * e) return;
  float b0 = bd[0];
  if (i < e) {
    int s = ei[i], d = ei[e + i];
    out[i] = Aarr[s] + Barr[d] + b0;
  } else {
    int j = i - e;
    int s = nei[j], d = nei[e + j];
    out[e + j] = Aarr[s] + Barr[d] + b0;
  }
}

extern "C" void kernel_launch(void* const* d_in, const int* in_sizes, int n_in,
                              void* d_out, int out_size, void* d_ws, size_t ws_size,
                              hipStream_t stream) {
  const float* x = (const float*)d_in[0];
  const int* ei = (const int*)d_in[1];
  const int* nei = (const int*)d_in[2];
  const int* y = (const int*)d_in[3];
  const int* tmask = (const int*)d_in[4];
  const float* W1 = (const float*)d_in[5];
  const float* b1 = (const float*)d_in[6];
  const float* W2 = (const float*)d_in[7];
  const float* b2 = (const float*)d_in[8];
  const float* Wx = (const float*)d_in[9];
  const float* bx = (const float*)d_in[10];
  const float* Wd = (const float*)d_in[11];
  const float* bd = (const float*)d_in[12];
  float* out = (float*)d_out;

  int n = in_sizes[3];        // N nodes
  int e = in_sizes[1] / 2;    // E edges

  char* ws = (char*)d_ws;
  size_t off = 0;
  auto alloc = [&](size_t bytes) -> void* {
    void* p = ws + off;
    off += (bytes + 511) & ~(size_t)511;
    return p;
  };
  ushort_t* xb = (ushort_t*)alloc((size_t)n * F * 2);
  ushort_t* WBt = (ushort_t*)alloc((size_t)NBCOL * F * 2);
  ushort_t* xw1 = (ushort_t*)alloc((size_t)n * H * 2);   // bf16
  float* xe = (float*)alloc((size_t)n * HX * 4);
  ushort_t* hb = (ushort_t*)alloc((size_t)n * H * 2);    // bf16
  float* hw2 = (float*)alloc((size_t)n * C * 4);
  float* dinv = (float*)alloc((size_t)n * 4);
  int* deg = (int*)alloc((size_t)n * 4);
  int* row_start = (int*)alloc((size_t)(n + 1) * 4);
  int* cursor = (int*)alloc((size_t)n * 4);
  int2* csr8 = (int2*)alloc((size_t)e * 8);
  int* part = (int*)alloc(1024 * 4);
  int* blockoff = (int*)alloc(1024 * 4);
  float* Aarr = (float*)alloc((size_t)n * 4);
  float* Barr = (float*)alloc((size_t)n * 4);

  const int* src = ei;
  const int* dst = ei + e;

  hipMemsetAsync(deg, 0, (size_t)n * 4, stream);

  int total8 = n * F / 8;
  int nbx = (total8 + 255) / 256;
  int nbw = (NBCOL * F + 255) / 256;
  int nbe = (e + 255) / 256;
  k_pre<<<nbx + nbw + nbe, 256, 0, stream>>>(x, xb, total8, W1, Wx, WBt, dst, deg, e,
                                             nbx, nbw);

  int nblk = (n + 255) / 256;  // 196 <= 256, required by k_scan_b
  k_scan_a<<<nblk, 256, 0, stream>>>(deg, part, n);
  k_scan_b<<<1, 256, 0, stream>>>(part, blockoff, nblk);
  k_scan_c<<<nblk, 256, 0, stream>>>(deg, blockoff, row_start, cursor, dinv, n, e);
  k_fill<<<(e + 255) / 256, 256, 0, stream>>>(src, dst, dinv, cursor, csr8, e);

  int ntiles = (n + 15) / 16;
  int ggrid = ntiles < 768 ? ntiles : 768;
  k_gemm1<<<ggrid, 256, 0, stream>>>(xb, WBt, bx, xw1, xe, n, ntiles);
  k_agg1<<<(n + 3) / 4, 256, 0, stream>>>(xw1, row_start, csr8, dinv, b1, hb, n);
  k_gemm2<<<(n * 4 + 255) / 256, 256, 0, stream>>>(hb, W2, hw2, n);
  k_agg2ab<<<(n * 16 + 255) / 256, 256, 0, stream>>>(hw2, row_start, csr8, dinv, b2, y,
                                                     tmask, xe, Wd, out + (size_t)2 * e,
                                                     Aarr, Barr, n);
  k_decode<<<(2 * e + 255) / 256, 256, 0, stream>>>(ei, nei, Aarr, Barr, bd, out, e);
}